// Round 7
// baseline (230.993 us; speedup 1.0000x reference)
//
#include <hip/hip_runtime.h>
#include <math.h>

#define BB 128
#define DD 256
#define SS 512
#define KK 50
#define HH 256
#define TS 64                // s-tile per block
#define NBLK (BB * SS / TS)  // 1024
#define BS (BB * SS)         // 65536

#define CHUNK 1024
#define NCH (BS / CHUNK)     // 64
#define NCHBLK (KK * NCH / 4) // 800 chunk blocks
#define TOPK 32
#define MAXSURV 512
#define NSUB (TS / 16)       // 4 survivor subtiles per tile

// workspace layout (float offsets)
#define TVN_OFF 0
#define TVNT_OFF (TVN_OFF + DD * KK)          // 12800
#define TPNT_OFF (TVNT_OFF + KK * DD)         // 25600
#define PREDACC_OFF (TPNT_OFF + KK * BS)
#define AE_OFF (PREDACC_OFF + BB * DD)        // +32768
#define SIM_OFF (AE_OFF + 1)
#define CNT_OFF (AE_OFF + 2)                  // surv_cnt
#define SIMD_OFF (AE_OFF + 3)                 // sim_done counter
#define LIST_OFF (AE_OFF + 4)                 // MAXSURV ints
#define CAND_OFF (LIST_OFF + MAXSURV)         // KK*NCH*TOPK floats
#define NZERO (BB * DD + 4)                   // predacc + ae + sim + cnt + simdone

// out layout: pred[0:256), 0.0@256, sim@257, far@258, nn[259:259+3276800), ae@3277059
#define OUT_NN_OFF 259
#define OUT_AE_IDX (OUT_NN_OFF + KK * BS)

__device__ __forceinline__ unsigned fkey(float f) {
  unsigned u = __float_as_uint(f);
  return (u & 0x80000000u) ? ~u : (u | 0x80000000u);
}
__device__ __forceinline__ float keyval(unsigned T) {
  unsigned u = (T & 0x80000000u) ? (T & 0x7FFFFFFFu) : ~T;
  return __uint_as_float(u);
}

// tvn + transposed copy; also zeroes predacc/scalar accumulators (replaces memset)
__global__ __launch_bounds__(256) void tvn_kernel(const float* __restrict__ tv,
                                                  float* __restrict__ tvn,
                                                  float* __restrict__ tvnT,
                                                  float* __restrict__ zbase) {
  __shared__ float red[256];
  const int k = blockIdx.x, t = threadIdx.x;
  {
    const int gid = k * 256 + t;                 // 12800 threads total
    for (int i = gid; i < NZERO; i += KK * 256) zbase[i] = 0.0f;
  }
  float v = tv[t * KK + k];
  red[t] = v * v;
  __syncthreads();
  for (int off = 128; off > 0; off >>= 1) {
    if (t < off) red[t] += red[t + off];
    __syncthreads();
  }
  float inv = 1.0f / fmaxf(sqrtf(red[0]), 1e-12f);
  const float nv = v * inv;
  tvn[t * KK + k] = nv;
  tvnT[k * DD + t] = nv;
}

// Block = 64-s tile, 4 waves; wave kb owns 13 k's (k=4j+kb); thread = one s.
// x via coalesced dword + depth-1 prefetch double-buffer; tvn via wave-uniform s_load.
__global__ __launch_bounds__(256, 4) void main_kernel(
    const float* __restrict__ f_input, const float* __restrict__ tvnT,
    float* __restrict__ out_nn, float* __restrict__ tpn_t,
    float* __restrict__ ae_acc, int* __restrict__ surv_cnt,
    int* __restrict__ surv_list) {
  __shared__ int wflag[4];

  const int blk = blockIdx.x;
  const int b = blk >> 3;
  const int s0 = (blk & 7) * TS;
  const int t = threadIdx.x;
  const int lane = t & 63;
  const int wid = t >> 6;
  const int kb = __builtin_amdgcn_readfirstlane(wid);  // scalar wave id -> scalar tvn addrs

  const float* tvk[13];
  bool kval[13];
  #pragma unroll
  for (int j = 0; j < 13; ++j) {
    const int k = 4 * j + kb;
    kval[j] = (k < KK);
    tvk[j] = tvnT + (size_t)(kval[j] ? k : (KK - 1)) * DD;
  }

  const float* xp = f_input + (size_t)b * DD * SS + s0 + lane;

  float acc[13];
  #pragma unroll
  for (int j = 0; j < 13; ++j) acc[j] = 0.0f;

  // depth-1 prefetch double buffer (4 d's per group)
  float xb[2][4];
  #pragma unroll
  for (int i = 0; i < 4; ++i) xb[0][i] = xp[(size_t)i * SS];

  float s2 = 0.0f;
  int buf = 0;
  for (int part = 0; part < 8; ++part) {
    float p = 0.0f;
    #pragma unroll
    for (int dd = 0; dd < 32; dd += 4) {
      const int d0 = part * 32 + dd;
      const int dn = (d0 + 4 < DD) ? (d0 + 4) : 0;  // clamp: harmless redundant prefetch
      #pragma unroll
      for (int i = 0; i < 4; ++i) xb[buf ^ 1][i] = xp[(size_t)(dn + i) * SS];
      const float x0 = xb[buf][0], x1 = xb[buf][1], x2 = xb[buf][2], x3 = xb[buf][3];
      // bit-exact order vs prior rounds: d-ascending within group, groups asc, parts folded asc
      p += x0 * x0; p += x1 * x1; p += x2 * x2; p += x3 * x3;
      #pragma unroll
      for (int j = 0; j < 13; ++j) {
        const float4 tq = *(const float4*)(tvk[j] + d0);  // wave-uniform -> s_load
        acc[j] += x0 * tq.x; acc[j] += x1 * tq.y;
        acc[j] += x2 * tq.z; acc[j] += x3 * tq.w;
      }
      buf ^= 1;
    }
    s2 = (part == 0) ? p : (s2 + p);
  }
  const float invn = 1.0f / fmaxf(sqrtf(s2), 1e-12f);

  bool m = false;
  const size_t gs = (size_t)b * SS + s0 + lane;
  #pragma unroll
  for (int j = 0; j < 13; ++j) {
    if (kval[j]) {
      const int k = 4 * j + kb;
      const float o = acc[j] * invn;
      tpn_t[(size_t)k * BS + gs] = o;
      m |= (o > 0.3f);
    }
  }

  const int w = __any((int)m);
  if (lane == 0) wflag[wid] = w;
  __syncthreads();
  const int any = wflag[0] | wflag[1] | wflag[2] | wflag[3];

  if (!any) {
    // fast path: nn = 0 for this tile; ae contribution = sum_s ||x_n||^2 = TS exactly
    float* ob = out_nn + ((size_t)b * SS + s0) * KK;
    for (int p2 = t; p2 < TS * KK; p2 += 256) ob[p2] = 0.0f;
    if (t == 0) atomicAdd(ae_acc, (float)TS);
    return;
  }
  if (t == 0) {
    const int idx = atomicAdd(surv_cnt, 1);
    if (idx < MAXSURV) surv_list[idx] = blk;
  }
}

// Fused: blocks [0,800) = per-wave exact top-32 of 1024-elem chunks;
// blocks [800,864) = survivor tiles (nn from tpn_t, out_nn, r1, r2, pred, ae).
__global__ __launch_bounds__(256) void chunk_surv_kernel(
    const float* __restrict__ tpn_t, float* __restrict__ cand,
    const float* __restrict__ f_input, const float* __restrict__ rec1,
    const float* __restrict__ rec2, const int* __restrict__ surv_cnt,
    const int* __restrict__ surv_list, float* __restrict__ out_nn,
    float* __restrict__ predacc, float* __restrict__ ae_acc) {
  __shared__ __align__(16) float NNk[KK * 20];   // [k][s16] stride 20
  __shared__ __align__(16) float R1t[HH * 20];   // [h][s16] stride 20
  __shared__ float nprt[16][17];
  __shared__ float nrm[16], invn[16];
  __shared__ float pm[8 * DD];
  __shared__ float red4[4];

  const int t = threadIdx.x;
  const int lane = t & 63, wid = t >> 6;

  if (blockIdx.x < NCHBLK) {
    // ---------- chunk top-32 path (no LDS, no barriers) ----------
    const int gchunk = blockIdx.x * 4 + wid;
    const int k = gchunk >> 6;
    const int c = gchunk & (NCH - 1);
    const float* row = tpn_t + (size_t)k * BS + c * CHUNK;

    float v[16];
    unsigned key[16];
    #pragma unroll
    for (int j = 0; j < 16; ++j) {
      v[j] = row[lane + j * 64];
      key[j] = fkey(v[j]);
    }
    unsigned T = 0;
    for (int bit = 31; bit >= 0; --bit) {
      const unsigned ct = T | (1u << bit);
      int cnt = 0;
      #pragma unroll
      for (int j = 0; j < 16; ++j) cnt += (key[j] >= ct) ? 1 : 0;
      #pragma unroll
      for (int off = 1; off < 64; off <<= 1) cnt += __shfl_xor(cnt, off);
      if (cnt >= TOPK) T = ct;
    }
    int cg = 0;
    #pragma unroll
    for (int j = 0; j < 16; ++j) cg += (key[j] > T) ? 1 : 0;
    int incl = cg;
    #pragma unroll
    for (int off = 1; off < 64; off <<= 1) {
      int y = __shfl_up(incl, off);
      if (lane >= off) incl += y;
    }
    const int excl = incl - cg;
    const int total_gt = __shfl(incl, 63);

    float* cb = cand + (size_t)gchunk * TOPK;
    int pos = excl;
    #pragma unroll
    for (int j = 0; j < 16; ++j) {
      if (key[j] > T) cb[pos++] = v[j];
    }
    if (lane < TOPK - total_gt) cb[total_gt + lane] = keyval(T);
    return;
  }

  // ---------- survivor path ----------
  const int bid = blockIdx.x - NCHBLK;   // 0..63
  int cnt = *surv_cnt;
  if (cnt > MAXSURV) cnt = MAXSURV;
  const int ntask = NSUB * cnt;

  for (int task = bid; task < ntask; task += 64) {
    const int blk = surv_list[task / NSUB];
    const int q = task % NSUB;
    const int b = blk >> 3;
    const int s0 = (blk & 7) * TS + q * 16;
    const float* fb = f_input + (size_t)b * DD * SS;
    const size_t gs0 = (size_t)b * SS + s0;

    // stage tpn rows for these 16 s
    for (int p = t; p < KK * 16; p += 256) {
      const int k = p >> 4, ss = p & 15;
      NNk[k * 20 + ss] = tpn_t[(size_t)k * BS + gs0 + ss];
    }
    // cooperative norms: 16 d-parts x 16 s, 16 unrolled independent loads each
    {
      const int ss = t & 15, part = t >> 4;
      const float* xc = fb + (size_t)(part * 16) * SS + s0 + ss;
      float p = 0.0f;
      #pragma unroll
      for (int i = 0; i < 16; ++i) {
        const float v = xc[(size_t)i * SS];
        p += v * v;
      }
      nprt[part][ss] = p;
    }
    __syncthreads();
    if (t < 16) {
      float s2 = 0.0f;
      #pragma unroll
      for (int i = 0; i < 16; ++i) s2 += nprt[i][t];
      const float n = fmaxf(sqrtf(s2), 1e-12f);
      nrm[t] = n;
      invn[t] = 1.0f / n;
      float sm = 0.0f;
      for (int k = 0; k < KK; ++k) {
        const float tpn = NNk[k * 20 + t];
        sm += (tpn > 0.3f) ? tpn * n : 0.0f;
      }
      const float idv = 1.0f / (sm + 0.001f + 1e-8f);
      for (int k = 0; k < KK; ++k) {
        const float tpn = NNk[k * 20 + t];
        NNk[k * 20 + t] = (tpn > 0.3f) ? tpn * n * idv : 0.0f;
      }
    }
    __syncthreads();

    // write out_nn for these 16 s (scalar: out_nn only 4B-aligned)
    for (int p = t; p < 16 * KK; p += 256) {
      const int ss = p / KK, k = p - ss * KK;
      out_nn[(gs0 + ss) * KK + k] = NNk[k * 20 + ss];
    }

    // phase 4: r1[h=t][s] = relu(nn . rec1) — direct coalesced rec1 loads (no reg-array!)
    {
      float a[16];
      #pragma unroll
      for (int i = 0; i < 16; ++i) a[i] = 0.0f;
      #pragma unroll 2
      for (int k = 0; k < KK; ++k) {
        const float r = rec1[k * HH + t];
        const float4* np = (const float4*)&NNk[k * 20];
        #pragma unroll
        for (int qq = 0; qq < 4; ++qq) {
          const float4 nv = np[qq];
          a[qq * 4 + 0] += nv.x * r;
          a[qq * 4 + 1] += nv.y * r;
          a[qq * 4 + 2] += nv.z * r;
          a[qq * 4 + 3] += nv.w * r;
        }
      }
      #pragma unroll
      for (int i = 0; i < 16; ++i) R1t[t * 20 + i] = fmaxf(a[i], 0.0f);
    }
    __syncthreads();

    // phase 5: r2 = r1 @ rec2; per thread 2s x 8d; h unrolled x8 with batch prefetch
    const int tx = t & 31, ty = t >> 5;
    const int d0 = tx * 8, sb = ty * 2;
    float c2[2][8];
    #pragma unroll
    for (int i = 0; i < 2; ++i)
      #pragma unroll
      for (int j = 0; j < 8; ++j) c2[i][j] = 0.0f;
    for (int h0 = 0; h0 < HH; h0 += 8) {
      float4 B0[8], B1[8];
      #pragma unroll
      for (int u = 0; u < 8; ++u) {
        B0[u] = *(const float4*)(rec2 + (h0 + u) * DD + d0);
        B1[u] = *(const float4*)(rec2 + (h0 + u) * DD + d0 + 4);
      }
      #pragma unroll
      for (int u = 0; u < 8; ++u) {
        const float2 a01 = *(const float2*)(&R1t[(h0 + u) * 20 + sb]);
        const float bv[8] = {B0[u].x, B0[u].y, B0[u].z, B0[u].w,
                             B1[u].x, B1[u].y, B1[u].z, B1[u].w};
        #pragma unroll
        for (int j = 0; j < 8; ++j) {
          c2[0][j] += a01.x * bv[j];
          c2[1][j] += a01.y * bv[j];
        }
      }
    }
    #pragma unroll
    for (int j = 0; j < 8; ++j) pm[ty * DD + d0 + j] = c2[0][j] + c2[1][j];
    __syncthreads();
    {
      float sum = 0.0f;
      #pragma unroll
      for (int r = 0; r < 8; ++r) sum += pm[r * DD + t];
      atomicAdd(&predacc[(size_t)b * DD + t], sum);
    }
    float e = 0.0f;
    #pragma unroll
    for (int j = 0; j < 8; ++j) {
      #pragma unroll
      for (int i = 0; i < 2; ++i) {
        const float x = fb[(size_t)(d0 + j) * SS + s0 + sb + i];
        const float diff = x * invn[sb + i] - c2[i][j];
        e += diff * diff;
      }
    }
    #pragma unroll
    for (int off = 1; off < 64; off <<= 1) e += __shfl_xor(e, off);
    if (lane == 0) red4[wid] = e;
    __syncthreads();
    if (t == 0) atomicAdd(ae_acc, red4[0] + red4[1] + red4[2] + red4[3]);
    __syncthreads();  // LDS reuse next task
  }
}

// Fused: blocks [0,128) pred head (+block0: far, out[256], ae);
// blocks [128,178) top-32 merge per concept; last merge finisher writes out[257].
__global__ __launch_bounds__(256) void merge_finalize_kernel(
    const float* __restrict__ cand, const float* __restrict__ predacc,
    const float* __restrict__ Wc, const float* __restrict__ bc,
    const float* __restrict__ ae_acc, float* __restrict__ sim_acc,
    unsigned* __restrict__ sim_done, const float* __restrict__ tvn,
    float* __restrict__ out) {
  __shared__ float r0[256], r1[256];
  const int blk = blockIdx.x;
  const int t = threadIdx.x;

  if (blk >= BB) {
    // ---- merge path: one wave, concept k ----
    if (t < 64) {
      const int k = blk - BB;
      const int lane = t;
      const float* row = cand + (size_t)k * (NCH * TOPK);
      float v[32];
      unsigned key[32];
      #pragma unroll
      for (int j = 0; j < 32; ++j) {
        v[j] = row[lane + j * 64];
        key[j] = fkey(v[j]);
      }
      unsigned T = 0;
      for (int bit = 31; bit >= 0; --bit) {
        const unsigned ct = T | (1u << bit);
        int cnt = 0;
        #pragma unroll
        for (int j = 0; j < 32; ++j) cnt += (key[j] >= ct) ? 1 : 0;
        #pragma unroll
        for (int off = 1; off < 64; off <<= 1) cnt += __shfl_xor(cnt, off);
        if (cnt >= TOPK) T = ct;
      }
      float s = 0.0f;
      int cgt = 0;
      #pragma unroll
      for (int j = 0; j < 32; ++j) {
        if (key[j] > T) { s += v[j]; cgt++; }
      }
      #pragma unroll
      for (int off = 1; off < 64; off <<= 1) {
        s += __shfl_xor(s, off);
        cgt += __shfl_xor(cgt, off);
      }
      if (lane == 0) {
        atomicAdd(sim_acc, s + (float)(TOPK - cgt) * keyval(T));
        __threadfence();
        const unsigned c = atomicAdd(sim_done, 1u);
        if (c == KK - 1) {               // last finisher: total is complete
          __threadfence();
          const float tot = atomicAdd(sim_acc, 0.0f);
          out[257] = -tot * (1.0f / (float)(KK * TOPK));
        }
      }
    }
    return;
  }

  // ---- finalize path: pred head for b = blk ----
  const float s = predacc[(size_t)blk * DD + t];
  r0[t] = s * Wc[t * 2 + 0];
  r1[t] = s * Wc[t * 2 + 1];
  __syncthreads();
  for (int off = 128; off > 0; off >>= 1) {
    if (t < off) { r0[t] += r0[t + off]; r1[t] += r1[t + off]; }
    __syncthreads();
  }
  if (t == 0) {
    out[blk * 2 + 0] = r0[0] * (1.0f / (float)SS) + bc[0];
    out[blk * 2 + 1] = r1[0] * (1.0f / (float)SS) + bc[1];
    if (blk == 0) {
      out[256] = 0.0f;
      out[OUT_AE_IDX] = (*ae_acc) * (1.0f / ((float)BB * (float)SS * (float)DD));
    }
  }
  if (blk == 0) {
    // concept_far: sum(G) = sum_d (rowsum_d)^2 since G = tvn^T tvn
    __syncthreads();
    float rs = 0.0f;
    for (int k = 0; k < KK; ++k) rs += tvn[t * KK + k];
    r0[t] = rs * rs;
    __syncthreads();
    for (int off = 128; off > 0; off >>= 1) {
      if (t < off) r0[t] += r0[t + off];
      __syncthreads();
    }
    if (t == 0) out[258] = (r0[0] - (float)KK) / ((float)KK * (float)KK);
  }
}

extern "C" void kernel_launch(void* const* d_in, const int* in_sizes, int n_in,
                              void* d_out, int out_size, void* d_ws, size_t ws_size,
                              hipStream_t stream) {
  (void)in_sizes; (void)n_in; (void)out_size; (void)ws_size;
  const float* f_input = (const float*)d_in[0];
  const float* tv = (const float*)d_in[2];
  const float* rec1 = (const float*)d_in[3];
  const float* rec2 = (const float*)d_in[4];
  const float* Wc = (const float*)d_in[5];
  const float* bc = (const float*)d_in[6];

  float* out = (float*)d_out;
  float* ws = (float*)d_ws;
  float* tvn = ws + TVN_OFF;
  float* tvnT = ws + TVNT_OFF;
  float* tpn_t = ws + TPNT_OFF;
  float* predacc = ws + PREDACC_OFF;
  float* ae_acc = ws + AE_OFF;
  float* sim_acc = ws + SIM_OFF;
  int* surv_cnt = (int*)(ws + CNT_OFF);
  unsigned* sim_done = (unsigned*)(ws + SIMD_OFF);
  int* surv_list = (int*)(ws + LIST_OFF);
  float* cand = ws + CAND_OFF;

  tvn_kernel<<<KK, 256, 0, stream>>>(tv, tvn, tvnT, predacc);
  main_kernel<<<NBLK, 256, 0, stream>>>(f_input, tvnT, out + OUT_NN_OFF, tpn_t,
                                        ae_acc, surv_cnt, surv_list);
  chunk_surv_kernel<<<NCHBLK + 64, 256, 0, stream>>>(
      tpn_t, cand, f_input, rec1, rec2, surv_cnt, surv_list,
      out + OUT_NN_OFF, predacc, ae_acc);
  merge_finalize_kernel<<<BB + KK, 256, 0, stream>>>(
      cand, predacc, Wc, bc, ae_acc, sim_acc, sim_done, tvn, out);
}

// Round 8
// 226.369 us; speedup vs baseline: 1.0204x; 1.0204x over previous
//
#include <hip/hip_runtime.h>
#include <math.h>

#define BB 128
#define DD 256
#define SS 512
#define KK 50
#define HH 256
#define TS 128               // s-tile
#define NTILES (BB * SS / TS) // 512
#define NBLK (NTILES * 2)    // 1024 (x2 k-halves)
#define BS (BB * SS)         // 65536

#define CHUNK 1024
#define NCH (BS / CHUNK)     // 64
#define NCHBLK (KK * NCH / 4) // 800 chunk blocks
#define TOPK 32
#define MAXSURV 512
#define NSUB (TS / 16)       // 8 survivor subtiles per tile

// workspace layout (float offsets)
#define TVN_OFF 0
#define TVNT_OFF (TVN_OFF + DD * KK)          // 12800
#define TPNT_OFF (TVNT_OFF + KK * DD)         // 25600
#define PREDACC_OFF (TPNT_OFF + KK * BS)
#define AE_OFF (PREDACC_OFF + BB * DD)        // +32768
#define SIM_OFF (AE_OFF + 1)
#define CNT_OFF (AE_OFF + 2)                  // surv_cnt
#define SIMD_OFF (AE_OFF + 3)                 // sim_done counter
#define TFLAG_OFF (AE_OFF + 4)                // NTILES ints
#define TCNT_OFF (TFLAG_OFF + NTILES)         // NTILES ints
#define NZERO (BB * DD + 4 + 2 * NTILES)      // contiguous zero region from PREDACC
#define LIST_OFF (TCNT_OFF + NTILES)          // MAXSURV ints (no zeroing needed)
#define CAND_OFF (LIST_OFF + MAXSURV)         // KK*NCH*TOPK floats

// out layout: pred[0:256), 0.0@256, sim@257, far@258, nn[259:259+3276800), ae@3277059
#define OUT_NN_OFF 259
#define OUT_AE_IDX (OUT_NN_OFF + KK * BS)

__device__ __forceinline__ unsigned fkey(float f) {
  unsigned u = __float_as_uint(f);
  return (u & 0x80000000u) ? ~u : (u | 0x80000000u);
}
__device__ __forceinline__ float keyval(unsigned T) {
  unsigned u = (T & 0x80000000u) ? (T & 0x7FFFFFFFu) : ~T;
  return __uint_as_float(u);
}

// tvn + transposed copy; also zeroes predacc/scalars/tile flags (replaces memset)
__global__ __launch_bounds__(256) void tvn_kernel(const float* __restrict__ tv,
                                                  float* __restrict__ tvn,
                                                  float* __restrict__ tvnT,
                                                  float* __restrict__ zbase) {
  __shared__ float red[256];
  const int k = blockIdx.x, t = threadIdx.x;
  {
    const int gid = k * 256 + t;                 // 12800 threads total
    for (int i = gid; i < NZERO; i += KK * 256) zbase[i] = 0.0f;
  }
  float v = tv[t * KK + k];
  red[t] = v * v;
  __syncthreads();
  for (int off = 128; off > 0; off >>= 1) {
    if (t < off) red[t] += red[t + off];
    __syncthreads();
  }
  float inv = 1.0f / fmaxf(sqrtf(red[0]), 1e-12f);
  const float nv = v * inv;
  tvn[t * KK + k] = nv;
  tvnT[k * DD + t] = nv;
}

// blk = tile*2 + half. Wave owns k = kb + 8j (kb = half*4+wid, j<7); thread = s-pair (float2).
// x: coalesced dwordx2 + depth-1 prefetch; tvn: wave-uniform s_load.
// Tile epilogue (zero-fill / survivor record) done by the 2nd-arriving block via tile_cnt.
__global__ __launch_bounds__(256, 4) void main_kernel(
    const float* __restrict__ f_input, const float* __restrict__ tvnT,
    float* __restrict__ out_nn, float* __restrict__ tpn_t,
    float* __restrict__ ae_acc, int* __restrict__ surv_cnt,
    int* __restrict__ surv_list, int* __restrict__ tile_flag,
    int* __restrict__ tile_cnt) {
  __shared__ int wflag[4];
  __shared__ int decision;   // 1 = zero-fill tile, 0 = nothing

  const int blk = blockIdx.x;
  const int tile = blk >> 1;
  const int half = blk & 1;
  const int b = tile >> 2;
  const int s0 = (tile & 3) * TS;
  const int t = threadIdx.x;
  const int lane = t & 63;
  const int wid = t >> 6;
  const int kb = __builtin_amdgcn_readfirstlane(half * 4 + wid);  // 0..7, wave-uniform

  const float* tvk[7];
  bool kval[7];
  #pragma unroll
  for (int j = 0; j < 7; ++j) {
    const int k = kb + 8 * j;
    kval[j] = (k < KK);
    tvk[j] = tvnT + (size_t)(kval[j] ? k : (KK - 1)) * DD;
  }

  const float* xp = f_input + (size_t)b * DD * SS + s0 + 2 * lane;

  float acc0[7], acc1[7];
  #pragma unroll
  for (int j = 0; j < 7; ++j) { acc0[j] = 0.0f; acc1[j] = 0.0f; }

  // depth-1 prefetch double buffer, 4 d's per group
  float2 xb[2][4];
  #pragma unroll
  for (int i = 0; i < 4; ++i) xb[0][i] = *(const float2*)(xp + (size_t)i * SS);

  float s2_0 = 0.0f, s2_1 = 0.0f;
  int buf = 0;
  for (int part = 0; part < 8; ++part) {
    float p0 = 0.0f, p1 = 0.0f;
    #pragma unroll
    for (int dd = 0; dd < 32; dd += 4) {
      const int d0 = part * 32 + dd;
      const int dn = (d0 + 4 < DD) ? (d0 + 4) : 0;   // clamp: harmless redundant prefetch
      #pragma unroll
      for (int i = 0; i < 4; ++i) xb[buf ^ 1][i] = *(const float2*)(xp + (size_t)(dn + i) * SS);
      const float2 xa = xb[buf][0], xc2 = xb[buf][1], xc3 = xb[buf][2], xc4 = xb[buf][3];
      // bit-exact chains: d-ascending per (k,s); norm 4 terms/group, parts folded asc
      p0 += xa.x * xa.x; p0 += xc2.x * xc2.x; p0 += xc3.x * xc3.x; p0 += xc4.x * xc4.x;
      p1 += xa.y * xa.y; p1 += xc2.y * xc2.y; p1 += xc3.y * xc3.y; p1 += xc4.y * xc4.y;
      #pragma unroll
      for (int j = 0; j < 7; ++j) {
        const float4 tq = *(const float4*)(tvk[j] + d0);  // wave-uniform -> s_load
        acc0[j] += xa.x * tq.x; acc0[j] += xc2.x * tq.y;
        acc0[j] += xc3.x * tq.z; acc0[j] += xc4.x * tq.w;
        acc1[j] += xa.y * tq.x; acc1[j] += xc2.y * tq.y;
        acc1[j] += xc3.y * tq.z; acc1[j] += xc4.y * tq.w;
      }
      buf ^= 1;
    }
    s2_0 = (part == 0) ? p0 : (s2_0 + p0);
    s2_1 = (part == 0) ? p1 : (s2_1 + p1);
  }
  const float i0 = 1.0f / fmaxf(sqrtf(s2_0), 1e-12f);
  const float i1 = 1.0f / fmaxf(sqrtf(s2_1), 1e-12f);

  bool m = false;
  const size_t gs = (size_t)b * SS + s0 + 2 * lane;
  #pragma unroll
  for (int j = 0; j < 7; ++j) {
    if (kval[j]) {
      const int k = kb + 8 * j;
      float2 o;
      o.x = acc0[j] * i0;
      o.y = acc1[j] * i1;
      *(float2*)(tpn_t + (size_t)k * BS + gs) = o;
      m = m | (o.x > 0.3f) | (o.y > 0.3f);
    }
  }

  const int w = __any((int)m);
  if (lane == 0) wflag[wid] = w;
  __syncthreads();
  const int blockAny = wflag[0] | wflag[1] | wflag[2] | wflag[3];

  if (t == 0) {
    const int old = atomicOr(&tile_flag[tile], blockAny);
    const int done = atomicAdd(&tile_cnt[tile], 1);
    int dec = 0;
    if (done == 1) {               // second finisher: union is complete
      const int fl = old | blockAny;
      if (fl) {
        const int idx = atomicAdd(surv_cnt, 1);
        if (idx < MAXSURV) surv_list[idx] = tile;
      } else {
        atomicAdd(ae_acc, (float)TS);  // sum_s ||x_n||^2 = TS exactly
        dec = 1;
      }
    }
    decision = dec;
  }
  __syncthreads();
  if (decision) {
    float* ob = out_nn + ((size_t)b * SS + s0) * KK;
    for (int p2 = t; p2 < TS * KK; p2 += 256) ob[p2] = 0.0f;
  }
}

// Fused: blocks [0,800) = per-wave exact top-32 of 1024-elem chunks;
// blocks [800,864) = survivor tiles (nn from tpn_t, out_nn, r1, r2, pred, ae).
__global__ __launch_bounds__(256) void chunk_surv_kernel(
    const float* __restrict__ tpn_t, float* __restrict__ cand,
    const float* __restrict__ f_input, const float* __restrict__ rec1,
    const float* __restrict__ rec2, const int* __restrict__ surv_cnt,
    const int* __restrict__ surv_list, float* __restrict__ out_nn,
    float* __restrict__ predacc, float* __restrict__ ae_acc) {
  __shared__ __align__(16) float NNk[KK * 20];   // [k][s16] stride 20
  __shared__ __align__(16) float R1t[HH * 20];   // [h][s16] stride 20
  __shared__ float nprt[16][17];
  __shared__ float nrm[16], invn[16];
  __shared__ float pm[8 * DD];
  __shared__ float red4[4];

  const int t = threadIdx.x;
  const int lane = t & 63, wid = t >> 6;

  if (blockIdx.x < NCHBLK) {
    // ---------- chunk top-32 path (no LDS, no barriers) ----------
    const int gchunk = blockIdx.x * 4 + wid;
    const int k = gchunk >> 6;
    const int c = gchunk & (NCH - 1);
    const float* row = tpn_t + (size_t)k * BS + c * CHUNK;

    float v[16];
    unsigned key[16];
    #pragma unroll
    for (int j = 0; j < 16; ++j) {
      v[j] = row[lane + j * 64];
      key[j] = fkey(v[j]);
    }
    unsigned T = 0;
    for (int bit = 31; bit >= 0; --bit) {
      const unsigned ct = T | (1u << bit);
      int cnt = 0;
      #pragma unroll
      for (int j = 0; j < 16; ++j) cnt += (key[j] >= ct) ? 1 : 0;
      #pragma unroll
      for (int off = 1; off < 64; off <<= 1) cnt += __shfl_xor(cnt, off);
      if (cnt >= TOPK) T = ct;
    }
    int cg = 0;
    #pragma unroll
    for (int j = 0; j < 16; ++j) cg += (key[j] > T) ? 1 : 0;
    int incl = cg;
    #pragma unroll
    for (int off = 1; off < 64; off <<= 1) {
      int y = __shfl_up(incl, off);
      if (lane >= off) incl += y;
    }
    const int excl = incl - cg;
    const int total_gt = __shfl(incl, 63);

    float* cb = cand + (size_t)gchunk * TOPK;
    int pos = excl;
    #pragma unroll
    for (int j = 0; j < 16; ++j) {
      if (key[j] > T) cb[pos++] = v[j];
    }
    if (lane < TOPK - total_gt) cb[total_gt + lane] = keyval(T);
    return;
  }

  // ---------- survivor path ----------
  const int bid = blockIdx.x - NCHBLK;   // 0..63
  int cnt = *surv_cnt;
  if (cnt > MAXSURV) cnt = MAXSURV;
  const int ntask = NSUB * cnt;

  for (int task = bid; task < ntask; task += 64) {
    const int tile = surv_list[task / NSUB];
    const int q = task % NSUB;
    const int b = tile >> 2;
    const int s0 = (tile & 3) * TS + q * 16;
    const float* fb = f_input + (size_t)b * DD * SS;
    const size_t gs0 = (size_t)b * SS + s0;

    // stage tpn rows for these 16 s
    for (int p = t; p < KK * 16; p += 256) {
      const int k = p >> 4, ss = p & 15;
      NNk[k * 20 + ss] = tpn_t[(size_t)k * BS + gs0 + ss];
    }
    // cooperative norms: 16 d-parts x 16 s, 16 unrolled independent loads each
    {
      const int ss = t & 15, part = t >> 4;
      const float* xc = fb + (size_t)(part * 16) * SS + s0 + ss;
      float p = 0.0f;
      #pragma unroll
      for (int i = 0; i < 16; ++i) {
        const float v = xc[(size_t)i * SS];
        p += v * v;
      }
      nprt[part][ss] = p;
    }
    __syncthreads();
    if (t < 16) {
      float s2 = 0.0f;
      #pragma unroll
      for (int i = 0; i < 16; ++i) s2 += nprt[i][t];
      const float n = fmaxf(sqrtf(s2), 1e-12f);
      nrm[t] = n;
      invn[t] = 1.0f / n;
      float sm = 0.0f;
      for (int k = 0; k < KK; ++k) {
        const float tpn = NNk[k * 20 + t];
        sm += (tpn > 0.3f) ? tpn * n : 0.0f;
      }
      const float idv = 1.0f / (sm + 0.001f + 1e-8f);
      for (int k = 0; k < KK; ++k) {
        const float tpn = NNk[k * 20 + t];
        NNk[k * 20 + t] = (tpn > 0.3f) ? tpn * n * idv : 0.0f;
      }
    }
    __syncthreads();

    // write out_nn for these 16 s (scalar: out_nn only 4B-aligned)
    for (int p = t; p < 16 * KK; p += 256) {
      const int ss = p / KK, k = p - ss * KK;
      out_nn[(gs0 + ss) * KK + k] = NNk[k * 20 + ss];
    }

    // phase 4: r1[h=t][s] = relu(nn . rec1)
    {
      float a[16];
      #pragma unroll
      for (int i = 0; i < 16; ++i) a[i] = 0.0f;
      #pragma unroll 2
      for (int k = 0; k < KK; ++k) {
        const float r = rec1[k * HH + t];
        const float4* np = (const float4*)&NNk[k * 20];
        #pragma unroll
        for (int qq = 0; qq < 4; ++qq) {
          const float4 nv = np[qq];
          a[qq * 4 + 0] += nv.x * r;
          a[qq * 4 + 1] += nv.y * r;
          a[qq * 4 + 2] += nv.z * r;
          a[qq * 4 + 3] += nv.w * r;
        }
      }
      #pragma unroll
      for (int i = 0; i < 16; ++i) R1t[t * 20 + i] = fmaxf(a[i], 0.0f);
    }
    __syncthreads();

    // phase 5: r2 = r1 @ rec2; per thread 2s x 8d; h unrolled x8 with batch prefetch
    const int tx = t & 31, ty = t >> 5;
    const int d0 = tx * 8, sb = ty * 2;
    float c2[2][8];
    #pragma unroll
    for (int i = 0; i < 2; ++i)
      #pragma unroll
      for (int j = 0; j < 8; ++j) c2[i][j] = 0.0f;
    for (int h0 = 0; h0 < HH; h0 += 8) {
      float4 B0[8], B1[8];
      #pragma unroll
      for (int u = 0; u < 8; ++u) {
        B0[u] = *(const float4*)(rec2 + (h0 + u) * DD + d0);
        B1[u] = *(const float4*)(rec2 + (h0 + u) * DD + d0 + 4);
      }
      #pragma unroll
      for (int u = 0; u < 8; ++u) {
        const float2 a01 = *(const float2*)(&R1t[(h0 + u) * 20 + sb]);
        const float bv[8] = {B0[u].x, B0[u].y, B0[u].z, B0[u].w,
                             B1[u].x, B1[u].y, B1[u].z, B1[u].w};
        #pragma unroll
        for (int j = 0; j < 8; ++j) {
          c2[0][j] += a01.x * bv[j];
          c2[1][j] += a01.y * bv[j];
        }
      }
    }
    #pragma unroll
    for (int j = 0; j < 8; ++j) pm[ty * DD + d0 + j] = c2[0][j] + c2[1][j];
    __syncthreads();
    {
      float sum = 0.0f;
      #pragma unroll
      for (int r = 0; r < 8; ++r) sum += pm[r * DD + t];
      atomicAdd(&predacc[(size_t)b * DD + t], sum);
    }
    float e = 0.0f;
    #pragma unroll
    for (int j = 0; j < 8; ++j) {
      #pragma unroll
      for (int i = 0; i < 2; ++i) {
        const float x = fb[(size_t)(d0 + j) * SS + s0 + sb + i];
        const float diff = x * invn[sb + i] - c2[i][j];
        e += diff * diff;
      }
    }
    #pragma unroll
    for (int off = 1; off < 64; off <<= 1) e += __shfl_xor(e, off);
    if (lane == 0) red4[wid] = e;
    __syncthreads();
    if (t == 0) atomicAdd(ae_acc, red4[0] + red4[1] + red4[2] + red4[3]);
    __syncthreads();  // LDS reuse next task
  }
}

// Fused: blocks [0,128) pred head (+block0: far, out[256], ae);
// blocks [128,178) top-32 merge per concept; last merge finisher writes out[257].
__global__ __launch_bounds__(256) void merge_finalize_kernel(
    const float* __restrict__ cand, const float* __restrict__ predacc,
    const float* __restrict__ Wc, const float* __restrict__ bc,
    const float* __restrict__ ae_acc, float* __restrict__ sim_acc,
    unsigned* __restrict__ sim_done, const float* __restrict__ tvn,
    float* __restrict__ out) {
  __shared__ float r0[256], r1[256];
  const int blk = blockIdx.x;
  const int t = threadIdx.x;

  if (blk >= BB) {
    // ---- merge path: one wave, concept k ----
    if (t < 64) {
      const int k = blk - BB;
      const int lane = t;
      const float* row = cand + (size_t)k * (NCH * TOPK);
      float v[32];
      unsigned key[32];
      #pragma unroll
      for (int j = 0; j < 32; ++j) {
        v[j] = row[lane + j * 64];
        key[j] = fkey(v[j]);
      }
      unsigned T = 0;
      for (int bit = 31; bit >= 0; --bit) {
        const unsigned ct = T | (1u << bit);
        int cnt = 0;
        #pragma unroll
        for (int j = 0; j < 32; ++j) cnt += (key[j] >= ct) ? 1 : 0;
        #pragma unroll
        for (int off = 1; off < 64; off <<= 1) cnt += __shfl_xor(cnt, off);
        if (cnt >= TOPK) T = ct;
      }
      float s = 0.0f;
      int cgt = 0;
      #pragma unroll
      for (int j = 0; j < 32; ++j) {
        if (key[j] > T) { s += v[j]; cgt++; }
      }
      #pragma unroll
      for (int off = 1; off < 64; off <<= 1) {
        s += __shfl_xor(s, off);
        cgt += __shfl_xor(cgt, off);
      }
      if (lane == 0) {
        atomicAdd(sim_acc, s + (float)(TOPK - cgt) * keyval(T));
        __threadfence();
        const unsigned c = atomicAdd(sim_done, 1u);
        if (c == KK - 1) {               // last finisher: total is complete
          __threadfence();
          const float tot = atomicAdd(sim_acc, 0.0f);
          out[257] = -tot * (1.0f / (float)(KK * TOPK));
        }
      }
    }
    return;
  }

  // ---- finalize path: pred head for b = blk ----
  const float s = predacc[(size_t)blk * DD + t];
  r0[t] = s * Wc[t * 2 + 0];
  r1[t] = s * Wc[t * 2 + 1];
  __syncthreads();
  for (int off = 128; off > 0; off >>= 1) {
    if (t < off) { r0[t] += r0[t + off]; r1[t] += r1[t + off]; }
    __syncthreads();
  }
  if (t == 0) {
    out[blk * 2 + 0] = r0[0] * (1.0f / (float)SS) + bc[0];
    out[blk * 2 + 1] = r1[0] * (1.0f / (float)SS) + bc[1];
    if (blk == 0) {
      out[256] = 0.0f;
      out[OUT_AE_IDX] = (*ae_acc) * (1.0f / ((float)BB * (float)SS * (float)DD));
    }
  }
  if (blk == 0) {
    // concept_far: sum(G) = sum_d (rowsum_d)^2 since G = tvn^T tvn
    __syncthreads();
    float rs = 0.0f;
    for (int k = 0; k < KK; ++k) rs += tvn[t * KK + k];
    r0[t] = rs * rs;
    __syncthreads();
    for (int off = 128; off > 0; off >>= 1) {
      if (t < off) r0[t] += r0[t + off];
      __syncthreads();
    }
    if (t == 0) out[258] = (r0[0] - (float)KK) / ((float)KK * (float)KK);
  }
}

extern "C" void kernel_launch(void* const* d_in, const int* in_sizes, int n_in,
                              void* d_out, int out_size, void* d_ws, size_t ws_size,
                              hipStream_t stream) {
  (void)in_sizes; (void)n_in; (void)out_size; (void)ws_size;
  const float* f_input = (const float*)d_in[0];
  const float* tv = (const float*)d_in[2];
  const float* rec1 = (const float*)d_in[3];
  const float* rec2 = (const float*)d_in[4];
  const float* Wc = (const float*)d_in[5];
  const float* bc = (const float*)d_in[6];

  float* out = (float*)d_out;
  float* ws = (float*)d_ws;
  float* tvn = ws + TVN_OFF;
  float* tvnT = ws + TVNT_OFF;
  float* tpn_t = ws + TPNT_OFF;
  float* predacc = ws + PREDACC_OFF;
  float* ae_acc = ws + AE_OFF;
  float* sim_acc = ws + SIM_OFF;
  int* surv_cnt = (int*)(ws + CNT_OFF);
  unsigned* sim_done = (unsigned*)(ws + SIMD_OFF);
  int* tile_flag = (int*)(ws + TFLAG_OFF);
  int* tile_cnt = (int*)(ws + TCNT_OFF);
  int* surv_list = (int*)(ws + LIST_OFF);
  float* cand = ws + CAND_OFF;

  tvn_kernel<<<KK, 256, 0, stream>>>(tv, tvn, tvnT, predacc);
  main_kernel<<<NBLK, 256, 0, stream>>>(f_input, tvnT, out + OUT_NN_OFF, tpn_t,
                                        ae_acc, surv_cnt, surv_list,
                                        tile_flag, tile_cnt);
  chunk_surv_kernel<<<NCHBLK + 64, 256, 0, stream>>>(
      tpn_t, cand, f_input, rec1, rec2, surv_cnt, surv_list,
      out + OUT_NN_OFF, predacc, ae_acc);
  merge_finalize_kernel<<<BB + KK, 256, 0, stream>>>(
      cand, predacc, Wc, bc, ae_acc, sim_acc, sim_done, tvn, out);
}